// Round 3
// baseline (2249.476 us; speedup 1.0000x reference)
//
#include <hip/hip_runtime.h>
#include <stdint.h>

#define HIDDEN 256
#define NMOLS 5000
#define APM 30
#define NATOMS 150000
#define NBONDS 320000
#define MAXNB 6
#define AFD 133
#define BFD 147
#define A1 (NATOMS + 1)
#define B1 (NBONDS + 1)
#define KI 160    // MFMA K extent for W_i GEMM (147 -> 160)
#define KIP 168   // LDS row padding for W_i A-tile (336 B rows)
#define KO 416    // padded readout K (133 f_atoms + 27 pad + 256 amsg)

typedef __bf16 bfx8 __attribute__((ext_vector_type(8)));
typedef float fx4 __attribute__((ext_vector_type(4)));
typedef unsigned short u16x8 __attribute__((ext_vector_type(8)));
typedef unsigned int u32x4 __attribute__((ext_vector_type(4)));

__device__ __forceinline__ float b2f(unsigned short u) {
    union { unsigned int i; float f; } v; v.i = ((unsigned int)u) << 16; return v.f;
}
__device__ __forceinline__ unsigned short f2b(float f) {
    union { float f; unsigned int i; } v; v.f = f;
    unsigned int r = v.i + 0x7FFFu + ((v.i >> 16) & 1u);
    return (unsigned short)(r >> 16);
}

// ---------------- weight conversion / padding ----------------
__global__ void k_convw(const float* __restrict__ Wi, const float* __restrict__ Wh,
                        const float* __restrict__ Wo,
                        unsigned short* __restrict__ wi, unsigned short* __restrict__ wh,
                        unsigned short* __restrict__ wo) {
    int t = blockIdx.x * 256 + threadIdx.x;
    if (t < 256 * KI) {
        int n = t / KI, k = t % KI;
        wi[t] = (k < BFD) ? f2b(Wi[n * BFD + k]) : (unsigned short)0;
        return;
    }
    int t2 = t - 256 * KI;
    if (t2 < 256 * 256) {
        wh[t2] = f2b(Wh[t2]);
        return;
    }
    int t3 = t2 - 256 * 256;
    if (t3 < 256 * KO) {
        int n = t3 / KO, k = t3 % KO;
        float v = 0.f;
        if (k < AFD) v = Wo[n * (AFD + HIDDEN) + k];
        else if (k >= 160) v = Wo[n * (AFD + HIDDEN) + AFD + (k - 160)];
        wo[t3] = f2b(v);
    }
}

// ---------------- K1: inp = f_bonds @ Wi^T ; msg0 = relu(inp) ----------------
__global__ __launch_bounds__(256) void k_gemm_wi(
    const float* __restrict__ fb, const unsigned short* __restrict__ wi,
    unsigned short* __restrict__ inp, unsigned short* __restrict__ msg0)
{
    __shared__ float s_f32[64 * BFD];          // 37632 B; reused as bf16 C-buf (32768 B)
    __shared__ unsigned short s_bf[64 * KIP];  // 21504 B padded bf16 A-tile
    const int m0 = blockIdx.x * 64;
    const int tid = threadIdx.x;

    // stage 1: coalesced float4 flat copy (64*588 B region, 16B-aligned start)
    {
        const size_t base = (size_t)m0 * BFD;
        const size_t tot = (size_t)B1 * BFD;
        const float4* src4 = (const float4*)(fb + base);
#pragma unroll
        for (int i = 0; i < 10; ++i) {
            const int t4 = i * 256 + tid;
            if (t4 < (64 * BFD) / 4) {
                const size_t f = base + (size_t)t4 * 4;
                float4 v;
                if (f + 4 <= tot) {
                    v = src4[t4];
                } else {
                    v.x = (f + 0 < tot) ? fb[f + 0] : 0.f;
                    v.y = (f + 1 < tot) ? fb[f + 1] : 0.f;
                    v.z = (f + 2 < tot) ? fb[f + 2] : 0.f;
                    v.w = (f + 3 < tot) ? fb[f + 3] : 0.f;
                }
                *(float4*)(s_f32 + t4 * 4) = v;
            }
        }
    }
    __syncthreads();

    // stage 2: LDS f32 -> LDS bf16 padded tile
    {
        const int r = tid >> 2, p = tid & 3;
        const float* srow = s_f32 + r * BFD;
        unsigned short* drow = s_bf + r * KIP;
#pragma unroll
        for (int i = 0; i < 5; ++i) {
            const int c0 = (i * 4 + p) * 8;   // 0..152
            u16x8 o;
#pragma unroll
            for (int e = 0; e < 8; ++e) {
                float v = (c0 + e < BFD) ? srow[c0 + e] : 0.f;
                o[e] = f2b(v);
            }
            *(u16x8*)(drow + c0) = o;
        }
    }
    __syncthreads();

    const int wv = tid >> 6, ln = tid & 63;
    const int l15 = ln & 15, lhi = ln >> 4;
    fx4 acc[4][4];
#pragma unroll
    for (int a = 0; a < 4; ++a)
#pragma unroll
        for (int b = 0; b < 4; ++b)
#pragma unroll
            for (int q = 0; q < 4; ++q) acc[a][b][q] = 0.f;

#pragma unroll
    for (int ks = 0; ks < 5; ++ks) {
        const int kk = ks * 32 + lhi * 8;
        bfx8 af[4], bb[4];
#pragma unroll
        for (int mf = 0; mf < 4; ++mf) {
            const int rr = mf * 16 + l15;
            af[mf] = *(const bfx8*)(s_bf + rr * KIP + kk);
        }
#pragma unroll
        for (int nf = 0; nf < 4; ++nf) {
            const int n = wv * 64 + nf * 16 + l15;
            bb[nf] = *(const bfx8*)(wi + n * KI + kk);
        }
#pragma unroll
        for (int mf = 0; mf < 4; ++mf)
#pragma unroll
            for (int nf = 0; nf < 4; ++nf)
                acc[mf][nf] = __builtin_amdgcn_mfma_f32_16x16x32_bf16(af[mf], bb[nf], acc[mf][nf], 0, 0, 0);
    }

    // C roundtrip: bf16 C-tile [64][256] (XOR-swizzled) in s_f32's storage
    __syncthreads();
    unsigned short* cbuf = (unsigned short*)s_f32;
    {
        const int cb = wv * 64 + l15;
        const int rb = lhi * 4;
#pragma unroll
        for (int mf = 0; mf < 4; ++mf)
#pragma unroll
            for (int j = 0; j < 4; ++j) {
                const int row = mf * 16 + rb + j;
#pragma unroll
                for (int nf = 0; nf < 4; ++nf) {
                    const int col = cb + nf * 16;
                    const int byte = (row * 512) + (((col * 2) & ~15) ^ ((row & 7) << 4)) + ((col * 2) & 15);
                    *(unsigned short*)((char*)cbuf + byte) = f2b(acc[mf][nf][j]);
                }
            }
    }
    __syncthreads();
    // readback + vector stores (inp and relu(inp))
#pragma unroll
    for (int i = 0; i < 8; ++i) {
        const int row = i * 8 + (tid >> 5);
        const int col16 = tid & 31;
        const int byte = row * 512 + ((col16 * 16) ^ ((row & 7) << 4));
        u16x8 c = *(const u16x8*)((const char*)cbuf + byte);
        const int g = m0 + row;
        if (g < B1) {
            u16x8 m;
#pragma unroll
            for (int e = 0; e < 8; ++e) m[e] = (c[e] & 0x8000u) ? (unsigned short)0 : c[e];
            *(u16x8*)(inp + (size_t)g * HIDDEN + col16 * 8) = c;
            *(u16x8*)(msg0 + (size_t)g * HIDDEN + col16 * 8) = m;
        }
    }
}

// ---------------- K2: amsg[a] = sum_j msg[a2b[a][j]] ----------------
__global__ __launch_bounds__(256) void k_gather(
    const unsigned short* __restrict__ msg, const int* __restrict__ a2b,
    unsigned short* __restrict__ amsg)
{
    const int gt = blockIdx.x * 256 + threadIdx.x;
    const int atom = gt >> 5;
    const int s = gt & 31;
    if (atom >= A1) return;
    const int* nb = a2b + atom * MAXNB;
    float acc[8];
#pragma unroll
    for (int e = 0; e < 8; ++e) acc[e] = 0.f;
#pragma unroll
    for (int j = 0; j < MAXNB; ++j) {
        const int b = nb[j];
        u16x8 v = *(const u16x8*)(msg + (size_t)b * HIDDEN + s * 8);
#pragma unroll
        for (int e = 0; e < 8; ++e) acc[e] += b2f(v[e]);
    }
    u16x8 o;
#pragma unroll
    for (int e = 0; e < 8; ++e) o[e] = f2b(acc[e]);
    *(u16x8*)(amsg + (size_t)atom * HIDDEN + s * 8) = o;
}

// ---------------- K3: msgn = relu(inp + amsg[b2a]@Wh^T - msgp[b2revb]@Wh^T) ----------------
// Tile: 32 bonds x K=512 ([amsg_row | -msg_row]), sign-flip negation, LDS C-roundtrip.
__global__ __launch_bounds__(256) void k_gemm_wh(
    const unsigned short* __restrict__ amsg,
    const unsigned short* __restrict__ msgp,
    const int* __restrict__ b2a, const int* __restrict__ b2revb,
    const unsigned short* __restrict__ wh,
    const unsigned short* __restrict__ inp,
    unsigned short* __restrict__ msgn)
{
    __shared__ unsigned short lds[32 * 512];  // 32 KiB: rows of 1 KiB, XOR-swizzled
    const int m0 = blockIdx.x * 32;
    const int tid = threadIdx.x;

    // staging: pure copy (amsg) + sign-flip copy (msgp), no float math
    {
        const int r = tid >> 3, p = tid & 7;
        const int b = m0 + r;
        const bool ok = (b < B1);
        int i1 = 0, i2 = 0;
        if (ok) { i1 = b2a[b]; i2 = b2revb[b]; }
        const u32x4* s1 = (const u32x4*)(amsg + (size_t)i1 * HIDDEN);
        const u32x4* s2 = (const u32x4*)(msgp + (size_t)i2 * HIDDEN);
        char* base = (char*)lds + r * 1024;
        const int sw = (r & 7) << 4;
#pragma unroll
        for (int c = 0; c < 4; ++c) {
            const int ch = c * 8 + p;          // 16B chunk index 0..31
            u32x4 va = ok ? s1[ch] : (u32x4)(0u);
            *(u32x4*)(base + ((ch * 16) ^ sw)) = va;
            u32x4 vm = ok ? s2[ch] : (u32x4)(0u);
            vm ^= 0x80008000u;                 // negate both bf16 halves
            *(u32x4*)(base + (512 + ((ch * 16) ^ sw))) = vm;
        }
    }
    __syncthreads();

    const int wv = tid >> 6, ln = tid & 63;
    const int l15 = ln & 15, lhi = ln >> 4;
    fx4 acc[2][4];
#pragma unroll
    for (int a = 0; a < 2; ++a)
#pragma unroll
        for (int b = 0; b < 4; ++b)
#pragma unroll
            for (int q = 0; q < 4; ++q) acc[a][b][q] = 0.f;

#pragma unroll
    for (int ks = 0; ks < 16; ++ks) {
        const int sect = ks >> 3, k8 = ks & 7;
        const int kk = k8 * 32 + lhi * 8;      // col within section
        bfx8 af[2], bb[4];
#pragma unroll
        for (int mf = 0; mf < 2; ++mf) {
            const int rr = mf * 16 + l15;
            af[mf] = *(const bfx8*)((const char*)lds + rr * 1024 + sect * 512 + ((kk * 2) ^ ((rr & 7) << 4)));
        }
#pragma unroll
        for (int nf = 0; nf < 4; ++nf) {
            const int n = wv * 64 + nf * 16 + l15;
            bb[nf] = *(const bfx8*)(wh + n * 256 + kk);
        }
#pragma unroll
        for (int mf = 0; mf < 2; ++mf)
#pragma unroll
            for (int nf = 0; nf < 4; ++nf)
                acc[mf][nf] = __builtin_amdgcn_mfma_f32_16x16x32_bf16(af[mf], bb[nf], acc[mf][nf], 0, 0, 0);
    }

    // C roundtrip: bf16 [32][256] XOR-swizzled, reusing lds
    __syncthreads();
    {
        const int cb = wv * 64 + l15;
        const int rb = lhi * 4;
#pragma unroll
        for (int mf = 0; mf < 2; ++mf)
#pragma unroll
            for (int j = 0; j < 4; ++j) {
                const int row = mf * 16 + rb + j;
#pragma unroll
                for (int nf = 0; nf < 4; ++nf) {
                    const int col = cb + nf * 16;
                    const int byte = (row * 512) + (((col * 2) & ~15) ^ ((row & 7) << 4)) + ((col * 2) & 15);
                    *(unsigned short*)((char*)lds + byte) = f2b(acc[mf][nf][j]);
                }
            }
    }
    __syncthreads();
#pragma unroll
    for (int i = 0; i < 4; ++i) {
        const int row = i * 8 + (tid >> 5);
        const int col16 = tid & 31;
        const int byte = row * 512 + ((col16 * 16) ^ ((row & 7) << 4));
        u16x8 c = *(const u16x8*)((const char*)lds + byte);
        const int g = m0 + row;
        if (g < B1) {
            const size_t off = (size_t)g * HIDDEN + col16 * 8;
            u16x8 ip = *(const u16x8*)(inp + off);
            u16x8 o;
#pragma unroll
            for (int e = 0; e < 8; ++e) {
                float v = b2f(ip[e]) + b2f(c[e]);
                o[e] = f2b(v > 0.f ? v : 0.f);
            }
            *(u16x8*)(msgn + off) = o;
        }
    }
}

// ---------------- K4: atom_hiddens(bf16) = relu(concat(f_atoms, amsg) @ Wo^T + bo) ----------------
__global__ __launch_bounds__(256) void k_gemm_wo(
    const float* __restrict__ fa,
    const unsigned short* __restrict__ amsg,
    const unsigned short* __restrict__ wo,
    const float* __restrict__ bo,
    unsigned short* __restrict__ ah)
{
    __shared__ unsigned short lds[64 * KO];  // 53248 B; first 32 KiB reused as C-buf
    const int m0 = blockIdx.x * 64;
    const int tid = threadIdx.x;
    {
        const int r = tid >> 2, p = tid & 3;
        const int a = m0 + r;
        const bool ok = (a < A1);
        const float* src = fa + (size_t)a * AFD;
        unsigned short* drow = lds + r * KO;
#pragma unroll
        for (int i = 0; i < 13; ++i) {
            const int c0 = (i * 4 + p) * 8;
            u16x8 o;
            if (ok && c0 + 8 <= AFD) {
#pragma unroll
                for (int e = 0; e < 8; ++e) o[e] = f2b(src[c0 + e]);
            } else if (ok && c0 < AFD) {
#pragma unroll
                for (int e = 0; e < 8; ++e) o[e] = (c0 + e < AFD) ? f2b(src[c0 + e]) : (unsigned short)0;
            } else if (ok && c0 >= 160) {
                o = *(const u16x8*)(amsg + (size_t)a * HIDDEN + (c0 - 160));
            } else {
#pragma unroll
                for (int e = 0; e < 8; ++e) o[e] = 0;
            }
            *(u16x8*)(drow + c0) = o;
        }
    }
    __syncthreads();

    const int wv = tid >> 6, ln = tid & 63;
    const int l15 = ln & 15, lhi = ln >> 4;
    fx4 acc[4][4];
#pragma unroll
    for (int a = 0; a < 4; ++a)
#pragma unroll
        for (int b = 0; b < 4; ++b)
#pragma unroll
            for (int q = 0; q < 4; ++q) acc[a][b][q] = 0.f;

#pragma unroll
    for (int ks = 0; ks < 13; ++ks) {
        const int kk = ks * 32 + lhi * 8;
        bfx8 af[4], bb[4];
#pragma unroll
        for (int mf = 0; mf < 4; ++mf) {
            const int rr = mf * 16 + l15;
            af[mf] = *(const bfx8*)(lds + rr * KO + kk);
        }
#pragma unroll
        for (int nf = 0; nf < 4; ++nf) {
            const int n = wv * 64 + nf * 16 + l15;
            bb[nf] = *(const bfx8*)(wo + n * KO + kk);
        }
#pragma unroll
        for (int mf = 0; mf < 4; ++mf)
#pragma unroll
            for (int nf = 0; nf < 4; ++nf)
                acc[mf][nf] = __builtin_amdgcn_mfma_f32_16x16x32_bf16(af[mf], bb[nf], acc[mf][nf], 0, 0, 0);
    }

    __syncthreads();
    {
        const int cb = wv * 64 + l15;
        const int rb = lhi * 4;
#pragma unroll
        for (int mf = 0; mf < 4; ++mf)
#pragma unroll
            for (int j = 0; j < 4; ++j) {
                const int row = mf * 16 + rb + j;
#pragma unroll
                for (int nf = 0; nf < 4; ++nf) {
                    const int col = cb + nf * 16;
                    const int byte = (row * 512) + (((col * 2) & ~15) ^ ((row & 7) << 4)) + ((col * 2) & 15);
                    *(unsigned short*)((char*)lds + byte) = f2b(acc[mf][nf][j]);
                }
            }
    }
    __syncthreads();
#pragma unroll
    for (int i = 0; i < 8; ++i) {
        const int row = i * 8 + (tid >> 5);
        const int col16 = tid & 31;
        const int byte = row * 512 + ((col16 * 16) ^ ((row & 7) << 4));
        u16x8 c = *(const u16x8*)((const char*)lds + byte);
        const int g = m0 + row;
        if (g < A1) {
            fx4 bi0 = *(const fx4*)(bo + col16 * 8);
            fx4 bi1 = *(const fx4*)(bo + col16 * 8 + 4);
            u16x8 o;
#pragma unroll
            for (int e = 0; e < 8; ++e) {
                float v = b2f(c[e]) + (e < 4 ? bi0[e] : bi1[e - 4]);
                o[e] = f2b(v > 0.f ? v : 0.f);
            }
            *(u16x8*)(ah + (size_t)g * HIDDEN + col16 * 8) = o;
        }
    }
}

// ---------------- K5: per-molecule mean over 30 atoms (bf16 in, f32 out) ----------------
__global__ __launch_bounds__(256) void k_pool(const unsigned short* __restrict__ ah,
                                              float* __restrict__ out) {
    const int mol = blockIdx.x;
    const int h = threadIdx.x;
    const unsigned short* base = ah + ((size_t)(1 + mol * APM)) * HIDDEN + h;
    float s = 0.f;
#pragma unroll
    for (int i = 0; i < APM; ++i) s += b2f(base[(size_t)i * HIDDEN]);
    out[(size_t)mol * HIDDEN + h] = s * (1.0f / APM);
}

extern "C" void kernel_launch(void* const* d_in, const int* in_sizes, int n_in,
                              void* d_out, int out_size, void* d_ws, size_t ws_size,
                              hipStream_t stream)
{
    const float* f_atoms = (const float*)d_in[0];
    const float* f_bonds = (const float*)d_in[1];
    const int* a2b    = (const int*)d_in[2];
    const int* b2a    = (const int*)d_in[3];
    const int* b2revb = (const int*)d_in[4];
    const float* W_i  = (const float*)d_in[6];
    const float* W_h  = (const float*)d_in[7];
    const float* W_o  = (const float*)d_in[8];
    const float* b_o  = (const float*)d_in[9];
    float* out = (float*)d_out;

    char* ws = (char*)d_ws;
    size_t off = 0;
    auto alloc = [&](size_t n) { char* p = ws + off; off = (off + n + 255) & ~(size_t)255; return p; };
    unsigned short* wi   = (unsigned short*)alloc((size_t)256 * KI * 2);
    unsigned short* wh   = (unsigned short*)alloc((size_t)256 * 256 * 2);
    unsigned short* wo   = (unsigned short*)alloc((size_t)256 * KO * 2);
    unsigned short* inp  = (unsigned short*)alloc((size_t)B1 * HIDDEN * 2);
    unsigned short* msgA = (unsigned short*)alloc((size_t)B1 * HIDDEN * 2);
    unsigned short* msgB = (unsigned short*)alloc((size_t)B1 * HIDDEN * 2);
    unsigned short* amsg = (unsigned short*)alloc((size_t)A1 * HIDDEN * 2);
    unsigned short* ah = inp;  // overlay: inp is dead after the last k_gemm_wh

    k_convw<<<832, 256, 0, stream>>>(W_i, W_h, W_o, wi, wh, wo);

    const int gb64 = (B1 + 63) / 64;          // 5001
    const int gb32 = (B1 + 31) / 32;          // 10001
    const int ga = (A1 + 63) / 64;            // 2344
    const int gg = (A1 * 32 + 255) / 256;     // 18751

    // wi writes inp and msg0=relu(inp) (into msgB)
    k_gemm_wi<<<gb64, 256, 0, stream>>>(f_bonds, wi, inp, msgB);

    unsigned short* cur = msgB;
    unsigned short* nxt = msgA;
    for (int it = 0; it < 5; ++it) {
        k_gather<<<gg, 256, 0, stream>>>(cur, a2b, amsg);
        k_gemm_wh<<<gb32, 256, 0, stream>>>(amsg, cur, b2a, b2revb, wh, inp, nxt);
        unsigned short* t = cur; cur = nxt; nxt = t;
    }
    k_gather<<<gg, 256, 0, stream>>>(cur, a2b, amsg);
    k_gemm_wo<<<ga, 256, 0, stream>>>(f_atoms, amsg, wo, b_o, ah);
    k_pool<<<NMOLS, 256, 0, stream>>>(ah, out);
}

// Round 4
// 1766.206 us; speedup vs baseline: 1.2736x; 1.2736x over previous
//
#include <hip/hip_runtime.h>
#include <stdint.h>

#define HIDDEN 256
#define NMOLS 5000
#define APM 30
#define NATOMS 150000
#define NBONDS 320000
#define MAXNB 6
#define AFD 133
#define BFD 147
#define A1 (NATOMS + 1)
#define B1 (NBONDS + 1)
#define KI 160    // MFMA K extent for W_i GEMM (147 -> 160)
#define KIP 168   // LDS row padding for W_i A-tile (336 B rows)
#define KO 416    // padded readout K (133 f_atoms + 27 pad + 256 amsg)

typedef __bf16 bfx8 __attribute__((ext_vector_type(8)));
typedef float fx4 __attribute__((ext_vector_type(4)));
typedef unsigned short u16x8 __attribute__((ext_vector_type(8)));
typedef unsigned int u32x4 __attribute__((ext_vector_type(4)));

__device__ __forceinline__ float b2f(unsigned short u) {
    union { unsigned int i; float f; } v; v.i = ((unsigned int)u) << 16; return v.f;
}
__device__ __forceinline__ unsigned short f2b(float f) {
    union { float f; unsigned int i; } v; v.f = f;
    unsigned int r = v.i + 0x7FFFu + ((v.i >> 16) & 1u);
    return (unsigned short)(r >> 16);
}
__device__ __forceinline__ void gload_lds16(const void* g, void* l) {
    __builtin_amdgcn_global_load_lds(
        (const __attribute__((address_space(1))) unsigned int*)g,
        (__attribute__((address_space(3))) unsigned int*)l, 16, 0, 0);
}

// ---------------- weight conversion / padding ----------------
__global__ void k_convw(const float* __restrict__ Wi, const float* __restrict__ Wh,
                        const float* __restrict__ Wo,
                        unsigned short* __restrict__ wi, unsigned short* __restrict__ wh,
                        unsigned short* __restrict__ wo) {
    int t = blockIdx.x * 256 + threadIdx.x;
    if (t < 256 * KI) {
        int n = t / KI, k = t % KI;
        wi[t] = (k < BFD) ? f2b(Wi[n * BFD + k]) : (unsigned short)0;
        return;
    }
    int t2 = t - 256 * KI;
    if (t2 < 256 * 256) {
        wh[t2] = f2b(Wh[t2]);
        return;
    }
    int t3 = t2 - 256 * 256;
    if (t3 < 256 * KO) {
        int n = t3 / KO, k = t3 % KO;
        float v = 0.f;
        if (k < AFD) v = Wo[n * (AFD + HIDDEN) + k];
        else if (k >= 160) v = Wo[n * (AFD + HIDDEN) + AFD + (k - 160)];
        wo[t3] = f2b(v);
    }
}

// ---------------- K1: inp = f_bonds @ Wi^T ; msg0 = relu(inp) ----------------
__global__ __launch_bounds__(256) void k_gemm_wi(
    const float* __restrict__ fb, const unsigned short* __restrict__ wi,
    unsigned short* __restrict__ inp, unsigned short* __restrict__ msg0)
{
    __shared__ float s_f32[64 * BFD];          // 37632 B; reused as bf16 C-buf (32768 B)
    __shared__ unsigned short s_bf[64 * KIP];  // 21504 B padded bf16 A-tile
    const int m0 = blockIdx.x * 64;
    const int tid = threadIdx.x;

    {
        const size_t base = (size_t)m0 * BFD;
        const size_t tot = (size_t)B1 * BFD;
        const float4* src4 = (const float4*)(fb + base);
#pragma unroll
        for (int i = 0; i < 10; ++i) {
            const int t4 = i * 256 + tid;
            if (t4 < (64 * BFD) / 4) {
                const size_t f = base + (size_t)t4 * 4;
                float4 v;
                if (f + 4 <= tot) {
                    v = src4[t4];
                } else {
                    v.x = (f + 0 < tot) ? fb[f + 0] : 0.f;
                    v.y = (f + 1 < tot) ? fb[f + 1] : 0.f;
                    v.z = (f + 2 < tot) ? fb[f + 2] : 0.f;
                    v.w = (f + 3 < tot) ? fb[f + 3] : 0.f;
                }
                *(float4*)(s_f32 + t4 * 4) = v;
            }
        }
    }
    __syncthreads();

    {
        const int r = tid >> 2, p = tid & 3;
        const float* srow = s_f32 + r * BFD;
        unsigned short* drow = s_bf + r * KIP;
#pragma unroll
        for (int i = 0; i < 5; ++i) {
            const int c0 = (i * 4 + p) * 8;
            u16x8 o;
#pragma unroll
            for (int e = 0; e < 8; ++e) {
                float v = (c0 + e < BFD) ? srow[c0 + e] : 0.f;
                o[e] = f2b(v);
            }
            *(u16x8*)(drow + c0) = o;
        }
    }
    __syncthreads();

    const int wv = tid >> 6, ln = tid & 63;
    const int l15 = ln & 15, lhi = ln >> 4;
    fx4 acc[4][4];
#pragma unroll
    for (int a = 0; a < 4; ++a)
#pragma unroll
        for (int b = 0; b < 4; ++b)
#pragma unroll
            for (int q = 0; q < 4; ++q) acc[a][b][q] = 0.f;

#pragma unroll
    for (int ks = 0; ks < 5; ++ks) {
        const int kk = ks * 32 + lhi * 8;
        bfx8 af[4], bb[4];
#pragma unroll
        for (int mf = 0; mf < 4; ++mf) {
            const int rr = mf * 16 + l15;
            af[mf] = *(const bfx8*)(s_bf + rr * KIP + kk);
        }
#pragma unroll
        for (int nf = 0; nf < 4; ++nf) {
            const int n = wv * 64 + nf * 16 + l15;
            bb[nf] = *(const bfx8*)(wi + n * KI + kk);
        }
#pragma unroll
        for (int mf = 0; mf < 4; ++mf)
#pragma unroll
            for (int nf = 0; nf < 4; ++nf)
                acc[mf][nf] = __builtin_amdgcn_mfma_f32_16x16x32_bf16(af[mf], bb[nf], acc[mf][nf], 0, 0, 0);
    }

    __syncthreads();
    unsigned short* cbuf = (unsigned short*)s_f32;
    {
        const int cb = wv * 64 + l15;
        const int rb = lhi * 4;
#pragma unroll
        for (int mf = 0; mf < 4; ++mf)
#pragma unroll
            for (int j = 0; j < 4; ++j) {
                const int row = mf * 16 + rb + j;
#pragma unroll
                for (int nf = 0; nf < 4; ++nf) {
                    const int col = cb + nf * 16;
                    const int byte = (row * 512) + (((col * 2) & ~15) ^ ((row & 7) << 4)) + ((col * 2) & 15);
                    *(unsigned short*)((char*)cbuf + byte) = f2b(acc[mf][nf][j]);
                }
            }
    }
    __syncthreads();
#pragma unroll
    for (int i = 0; i < 8; ++i) {
        const int row = i * 8 + (tid >> 5);
        const int col16 = tid & 31;
        const int byte = row * 512 + ((col16 * 16) ^ ((row & 7) << 4));
        u16x8 c = *(const u16x8*)((const char*)cbuf + byte);
        const int g = m0 + row;
        if (g < B1) {
            u16x8 m;
#pragma unroll
            for (int e = 0; e < 8; ++e) m[e] = (c[e] & 0x8000u) ? (unsigned short)0 : c[e];
            *(u16x8*)(inp + (size_t)g * HIDDEN + col16 * 8) = c;
            *(u16x8*)(msg0 + (size_t)g * HIDDEN + col16 * 8) = m;
        }
    }
}

// ---------------- K_Z: Z = msg @ Wh^T (dense, streaming) ----------------
__global__ __launch_bounds__(256) void k_gemm_z(
    const unsigned short* __restrict__ msg,
    const unsigned short* __restrict__ wh,
    unsigned short* __restrict__ Z)
{
    __shared__ unsigned short lds[64 * 256];  // 32 KiB A-tile, XOR-swizzled storage
    const int m0 = blockIdx.x * 64;
    const int tid = threadIdx.x;
    const int wv = tid >> 6, ln = tid & 63;

    // staging: global_load_lds width=16, linear LDS dest, pre-swizzled SOURCE.
    // LDS byte p = row*512 + q holds global row (m0+row) byte (q ^ ((row&7)<<4)).
    {
        const int l2 = ln >> 5;           // 0..1
        const int q = (ln & 31) * 16;     // 16B chunk within row
#pragma unroll
        for (int r = 0; r < 8; ++r) {
            const int row = wv * 16 + r * 2 + l2;
            const size_t srcb = (size_t)(m0 + row) * 512 + (size_t)(q ^ ((row & 7) << 4));
            char* dst = (char*)lds + wv * 8192 + r * 1024;  // wave-uniform base
            gload_lds16((const char*)msg + srcb, dst);
        }
    }
    __syncthreads();

    const int l15 = ln & 15, lhi = ln >> 4;
    fx4 acc[4][4];
#pragma unroll
    for (int a = 0; a < 4; ++a)
#pragma unroll
        for (int b = 0; b < 4; ++b)
#pragma unroll
            for (int q = 0; q < 4; ++q) acc[a][b][q] = 0.f;

#pragma unroll
    for (int ks = 0; ks < 8; ++ks) {
        const int kk = ks * 32 + lhi * 8;
        bfx8 af[4], bb[4];
#pragma unroll
        for (int mf = 0; mf < 4; ++mf) {
            const int rr = mf * 16 + l15;
            af[mf] = *(const bfx8*)((const char*)lds + rr * 512 + ((kk * 2) ^ ((rr & 7) << 4)));
        }
#pragma unroll
        for (int nf = 0; nf < 4; ++nf) {
            const int n = wv * 64 + nf * 16 + l15;
            bb[nf] = *(const bfx8*)(wh + n * 256 + kk);
        }
#pragma unroll
        for (int mf = 0; mf < 4; ++mf)
#pragma unroll
            for (int nf = 0; nf < 4; ++nf)
                acc[mf][nf] = __builtin_amdgcn_mfma_f32_16x16x32_bf16(af[mf], bb[nf], acc[mf][nf], 0, 0, 0);
    }

    // C roundtrip -> coalesced u16x8 stores of Z
    __syncthreads();
    {
        const int cb = wv * 64 + l15;
        const int rb = lhi * 4;
#pragma unroll
        for (int mf = 0; mf < 4; ++mf)
#pragma unroll
            for (int j = 0; j < 4; ++j) {
                const int row = mf * 16 + rb + j;
#pragma unroll
                for (int nf = 0; nf < 4; ++nf) {
                    const int col = cb + nf * 16;
                    const int byte = (row * 512) + (((col * 2) & ~15) ^ ((row & 7) << 4)) + ((col * 2) & 15);
                    *(unsigned short*)((char*)lds + byte) = f2b(acc[mf][nf][j]);
                }
            }
    }
    __syncthreads();
#pragma unroll
    for (int i = 0; i < 8; ++i) {
        const int row = i * 8 + (tid >> 5);
        const int col16 = tid & 31;
        const int byte = row * 512 + ((col16 * 16) ^ ((row & 7) << 4));
        u16x8 c = *(const u16x8*)((const char*)lds + byte);
        const int g = m0 + row;
        if (g < B1) *(u16x8*)(Z + (size_t)g * HIDDEN + col16 * 8) = c;
    }
}

// ---------------- K_G: amsg[a] = sum_j src[a2b[a][j]] ----------------
__global__ __launch_bounds__(256) void k_gather(
    const unsigned short* __restrict__ msg, const int* __restrict__ a2b,
    unsigned short* __restrict__ amsg)
{
    const int gt = blockIdx.x * 256 + threadIdx.x;
    const int atom = gt >> 5;
    const int s = gt & 31;
    if (atom >= A1) return;
    const int* nb = a2b + atom * MAXNB;
    float acc[8];
#pragma unroll
    for (int e = 0; e < 8; ++e) acc[e] = 0.f;
#pragma unroll
    for (int j = 0; j < MAXNB; ++j) {
        const int b = nb[j];
        u16x8 v = *(const u16x8*)(msg + (size_t)b * HIDDEN + s * 8);
#pragma unroll
        for (int e = 0; e < 8; ++e) acc[e] += b2f(v[e]);
    }
    u16x8 o;
#pragma unroll
    for (int e = 0; e < 8; ++e) o[e] = f2b(acc[e]);
    *(u16x8*)(amsg + (size_t)atom * HIDDEN + s * 8) = o;
}

// ---------------- K_E: msgn[b] = relu(inp[b] + amsgZ[b2a[b]] - Z[b2revb[b]]) ----------------
__global__ __launch_bounds__(256) void k_eps(
    const unsigned short* __restrict__ inp,
    const unsigned short* __restrict__ amsgZ,
    const unsigned short* __restrict__ Z,
    const int* __restrict__ b2a, const int* __restrict__ b2revb,
    unsigned short* __restrict__ msgn)
{
    const int gt = blockIdx.x * 256 + threadIdx.x;
    const int b = gt >> 5;
    const int s = gt & 31;
    if (b >= B1) return;
    const int ia = b2a[b];
    const int ir = b2revb[b];
    const size_t off = (size_t)b * HIDDEN + s * 8;
    u16x8 vi = *(const u16x8*)(inp + off);
    u16x8 va = *(const u16x8*)(amsgZ + (size_t)ia * HIDDEN + s * 8);
    u16x8 vz = *(const u16x8*)(Z + (size_t)ir * HIDDEN + s * 8);
    u16x8 o;
#pragma unroll
    for (int e = 0; e < 8; ++e) {
        float v = b2f(vi[e]) + b2f(va[e]) - b2f(vz[e]);
        o[e] = f2b(v > 0.f ? v : 0.f);
    }
    *(u16x8*)(msgn + off) = o;
}

// ---------------- K4: atom_hiddens(bf16) = relu(concat(f_atoms, amsg) @ Wo^T + bo) ----------------
__global__ __launch_bounds__(256) void k_gemm_wo(
    const float* __restrict__ fa,
    const unsigned short* __restrict__ amsg,
    const unsigned short* __restrict__ wo,
    const float* __restrict__ bo,
    unsigned short* __restrict__ ah)
{
    __shared__ unsigned short lds[64 * KO];
    const int m0 = blockIdx.x * 64;
    const int tid = threadIdx.x;
    {
        const int r = tid >> 2, p = tid & 3;
        const int a = m0 + r;
        const bool ok = (a < A1);
        const float* src = fa + (size_t)a * AFD;
        unsigned short* drow = lds + r * KO;
#pragma unroll
        for (int i = 0; i < 13; ++i) {
            const int c0 = (i * 4 + p) * 8;
            u16x8 o;
            if (ok && c0 + 8 <= AFD) {
#pragma unroll
                for (int e = 0; e < 8; ++e) o[e] = f2b(src[c0 + e]);
            } else if (ok && c0 < AFD) {
#pragma unroll
                for (int e = 0; e < 8; ++e) o[e] = (c0 + e < AFD) ? f2b(src[c0 + e]) : (unsigned short)0;
            } else if (ok && c0 >= 160) {
                o = *(const u16x8*)(amsg + (size_t)a * HIDDEN + (c0 - 160));
            } else {
#pragma unroll
                for (int e = 0; e < 8; ++e) o[e] = 0;
            }
            *(u16x8*)(drow + c0) = o;
        }
    }
    __syncthreads();

    const int wv = tid >> 6, ln = tid & 63;
    const int l15 = ln & 15, lhi = ln >> 4;
    fx4 acc[4][4];
#pragma unroll
    for (int a = 0; a < 4; ++a)
#pragma unroll
        for (int b = 0; b < 4; ++b)
#pragma unroll
            for (int q = 0; q < 4; ++q) acc[a][b][q] = 0.f;

#pragma unroll
    for (int ks = 0; ks < 13; ++ks) {
        const int kk = ks * 32 + lhi * 8;
        bfx8 af[4], bb[4];
#pragma unroll
        for (int mf = 0; mf < 4; ++mf) {
            const int rr = mf * 16 + l15;
            af[mf] = *(const bfx8*)(lds + rr * KO + kk);
        }
#pragma unroll
        for (int nf = 0; nf < 4; ++nf) {
            const int n = wv * 64 + nf * 16 + l15;
            bb[nf] = *(const bfx8*)(wo + n * KO + kk);
        }
#pragma unroll
        for (int mf = 0; mf < 4; ++mf)
#pragma unroll
            for (int nf = 0; nf < 4; ++nf)
                acc[mf][nf] = __builtin_amdgcn_mfma_f32_16x16x32_bf16(af[mf], bb[nf], acc[mf][nf], 0, 0, 0);
    }

    __syncthreads();
    {
        const int cb = wv * 64 + l15;
        const int rb = lhi * 4;
#pragma unroll
        for (int mf = 0; mf < 4; ++mf)
#pragma unroll
            for (int j = 0; j < 4; ++j) {
                const int row = mf * 16 + rb + j;
#pragma unroll
                for (int nf = 0; nf < 4; ++nf) {
                    const int col = cb + nf * 16;
                    const int byte = (row * 512) + (((col * 2) & ~15) ^ ((row & 7) << 4)) + ((col * 2) & 15);
                    *(unsigned short*)((char*)lds + byte) = f2b(acc[mf][nf][j]);
                }
            }
    }
    __syncthreads();
#pragma unroll
    for (int i = 0; i < 8; ++i) {
        const int row = i * 8 + (tid >> 5);
        const int col16 = tid & 31;
        const int byte = row * 512 + ((col16 * 16) ^ ((row & 7) << 4));
        u16x8 c = *(const u16x8*)((const char*)lds + byte);
        const int g = m0 + row;
        if (g < A1) {
            fx4 bi0 = *(const fx4*)(bo + col16 * 8);
            fx4 bi1 = *(const fx4*)(bo + col16 * 8 + 4);
            u16x8 o;
#pragma unroll
            for (int e = 0; e < 8; ++e) {
                float v = b2f(c[e]) + (e < 4 ? bi0[e] : bi1[e - 4]);
                o[e] = f2b(v > 0.f ? v : 0.f);
            }
            *(u16x8*)(ah + (size_t)g * HIDDEN + col16 * 8) = o;
        }
    }
}

// ---------------- K5: per-molecule mean over 30 atoms ----------------
__global__ __launch_bounds__(256) void k_pool(const unsigned short* __restrict__ ah,
                                              float* __restrict__ out) {
    const int mol = blockIdx.x;
    const int h = threadIdx.x;
    const unsigned short* base = ah + ((size_t)(1 + mol * APM)) * HIDDEN + h;
    float s = 0.f;
#pragma unroll
    for (int i = 0; i < APM; ++i) s += b2f(base[(size_t)i * HIDDEN]);
    out[(size_t)mol * HIDDEN + h] = s * (1.0f / APM);
}

extern "C" void kernel_launch(void* const* d_in, const int* in_sizes, int n_in,
                              void* d_out, int out_size, void* d_ws, size_t ws_size,
                              hipStream_t stream)
{
    const float* f_atoms = (const float*)d_in[0];
    const float* f_bonds = (const float*)d_in[1];
    const int* a2b    = (const int*)d_in[2];
    const int* b2a    = (const int*)d_in[3];
    const int* b2revb = (const int*)d_in[4];
    const float* W_i  = (const float*)d_in[6];
    const float* W_h  = (const float*)d_in[7];
    const float* W_o  = (const float*)d_in[8];
    const float* b_o  = (const float*)d_in[9];
    float* out = (float*)d_out;

    char* ws = (char*)d_ws;
    size_t off = 0;
    auto alloc = [&](size_t n) { char* p = ws + off; off = (off + n + 255) & ~(size_t)255; return p; };
    unsigned short* wi   = (unsigned short*)alloc((size_t)256 * KI * 2);
    unsigned short* wh   = (unsigned short*)alloc((size_t)256 * 256 * 2);
    unsigned short* wo   = (unsigned short*)alloc((size_t)256 * KO * 2);
    unsigned short* inp  = (unsigned short*)alloc((size_t)B1 * HIDDEN * 2);
    unsigned short* msgX = (unsigned short*)alloc((size_t)B1 * HIDDEN * 2 + 65536); // +slop for staging overrun
    unsigned short* Zbuf = (unsigned short*)alloc((size_t)B1 * HIDDEN * 2 + 65536);
    unsigned short* amsg = (unsigned short*)alloc((size_t)A1 * HIDDEN * 2);
    unsigned short* ah = inp;  // overlay: inp is dead after the last k_eps

    k_convw<<<832, 256, 0, stream>>>(W_i, W_h, W_o, wi, wh, wo);

    const int gb64 = (B1 + 63) / 64;            // 5001
    const int ga = (A1 + 63) / 64;              // 2344
    const int gg = (A1 * 32 + 255) / 256;       // 18751
    const int ge = (B1 * 32 + 255) / 256;       // 40001

    // inp = f_bonds@Wi^T, msg0 = relu(inp) -> msgX
    k_gemm_wi<<<gb64, 256, 0, stream>>>(f_bonds, wi, inp, msgX);

    for (int it = 0; it < 5; ++it) {
        k_gemm_z<<<gb64, 256, 0, stream>>>(msgX, wh, Zbuf);       // Z = msg @ Wh^T
        k_gather<<<gg, 256, 0, stream>>>(Zbuf, a2b, amsg);        // amsgZ = gather-sum(Z)
        k_eps<<<ge, 256, 0, stream>>>(inp, amsg, Zbuf, b2a, b2revb, msgX); // msg' in place
    }
    k_gather<<<gg, 256, 0, stream>>>(msgX, a2b, amsg);
    k_gemm_wo<<<ga, 256, 0, stream>>>(f_atoms, amsg, wo, b_o, ah);
    k_pool<<<NMOLS, 256, 0, stream>>>(ah, out);
}